// Round 1
// 91.032 us; speedup vs baseline: 1.0845x; 1.0845x over previous
//
#include <hip/hip_runtime.h>
#include <math.h>

// SpikingModel: 500-step EIF recurrent net, B=16, N=4096, fp32.
// Round-8: closed-form no-spike certificate replaces the 500-step speculative
// integration on the common path.
//   spec_kernel   : per-block Y0-row zero-scan -> z0 (0 common / gated dense dot).
//                   Certificate: z0==0 && V0<=-55 && x0<=8  =>  V<=-55 is an
//                   invariant of the clamped reference map (V' <= -55.08, margin
//                   0.08 >> fp32 slop) => provably zero spikes => out==0 exactly,
//                   NO integration needed. Non-certified lanes fall back to the
//                   r7-proven speculative integrator (3-op chain, off-chain
//                   vmax/vmin latches) whose flags route to the exact fallback.
//   persist_kernel: r3-proven event-driven exact fallback, gated on flags,
//                   uniform early-exit when everything certified / spike-free.
//
// Soundness of skipping integration on certified lanes: the first spike globally
// (if any) must occur on a zero-feedback trajectory (Y feedback is identically
// the decayed Y0 until the first spike). Certified lanes provably never spike on
// their zero-feedback trajectory; non-certified lanes integrate it with
// conservative vmax (spike) / vmin (clamp-engagement) latches. Any latch =>
// sflags => persist recomputes ALL batch rows exactly, overwriting out.
//
// ws layout: zrec[16][4096] floats @ 0 ; sflags[256] ints @ float-off 65536.

#define NN 4096

// ---------------- certificate + speculative integrator ---------------------

__global__ __launch_bounds__(256) void spec_kernel(const float* __restrict__ W,
                                                   const float* __restrict__ x0,
                                                   const float* __restrict__ V0,
                                                   const float* __restrict__ Y0,
                                                   float* __restrict__ zrec,
                                                   int* __restrict__ sflags,
                                                   float* __restrict__ out) {
    __shared__ float yrow[NN];                   // 16 KB row stage (fallback only)
    __shared__ unsigned long long m[4];
    const int t = threadIdx.x;
    const int gid = blockIdx.x * 256 + t;        // 256 blocks x 256 = 65536
    const int b = blockIdx.x >> 4;               // 16 blocks per batch row
    const int n = gid & (NN - 1);

    // issue V0/x0 loads first: their HBM latency hides under the Y0 scan+barrier
    const float v0 = V0[gid];
    const float x  = x0[gid];

    // ---- Y0[b,:] zero-scan: 4 int4 per thread, bitwise OR (conservative) ---
    const int4* Yr4 = (const int4*)(Y0 + (size_t)b * NN);
    int4 o = {0, 0, 0, 0};
#pragma unroll
    for (int i = 0; i < 4; ++i) {
        int4 q = Yr4[i * 256 + t];
        o.x |= q.x; o.y |= q.y; o.z |= q.z; o.w |= q.w;
    }
    int ynz = __syncthreads_or(o.x | o.y | o.z | o.w);

    float z0 = 0.0f;
    if (ynz) {                                   // gated dense dot (never taken for
        const float4* Yr = (const float4*)(Y0 + (size_t)b * NN);  // zero Y0)
#pragma unroll
        for (int i = 0; i < 4; ++i)
            ((float4*)yrow)[i * 256 + t] = Yr[i * 256 + t];
        __syncthreads();
        const float4* Wr = (const float4*)(W + (size_t)n * NN);
        float4 a = {0.0f, 0.0f, 0.0f, 0.0f};
        for (int k = 0; k < NN / 4; ++k) {
            float4 y = ((const float4*)yrow)[k];
            float4 w = Wr[k];
            a.x = fmaf(y.x, w.x, a.x);
            a.y = fmaf(y.y, w.y, a.y);
            a.z = fmaf(y.z, w.z, a.z);
            a.w = fmaf(y.w, w.w, a.w);
        }
        z0 = (a.x + a.y) + (a.z + a.w);
    }
    zrec[gid] = z0;                              // fallback's Zrec(0); always written

    // ---- closed-form no-spike certificate ----------------------------------
    // For z0==0, Z_t == x (constant). If V<=-55 and x<=8:
    //   V' = 0.99V + 0.01(e^{V+55} + x - 72) <= -54.45 + 0.01(1 + 8 - 72) = -55.08
    // and the -85 clamp maps into [-85,-55]. So V<=-55 forever => never spikes
    // => exact contribution to out is 0. NaN-safe: NaN inputs fail the compares.
    const bool safe = (z0 == 0.0f) && (v0 <= -55.0f) && (x <= 8.0f);

    bool fb = false;
    if (!safe) {
        // ---- 500-step speculative integration, 3-op critical chain ---------
        // v' = 0.99 v + 0.01 e^{v+55} + czt   (czt = 0.01(x+z) - 0.72)
        // chain: fma(v,L2E,K55) -> v_exp -> fma(0.01,e,w);  w = fma(0.99,v,czt),
        // vmax, vmin latches are off-chain. Clamp speculated away: vmin < -85
        // (or NaN) routes to exact fallback. vmax >= 0 routes spikes to fallback.
        float v = v0;
        const float c = fmaf(0.01f, x, -0.72f);
        float vmax = v, vmin = v;
        const float L2E = 1.44269504088896f;
        const float K55 = 55.0f * 1.44269504088896f;

        if (z0 == 0.0f) {                        // czt constant
#pragma unroll 10
            for (int s = 0; s < 500; ++s) {
                float e = __builtin_amdgcn_exp2f(fmaf(v, L2E, K55));
                float w = fmaf(0.99f, v, c);
                v = fmaf(0.01f, e, w);
                vmax = fmaxf(vmax, v);
                vmin = fminf(vmin, v);
            }
        } else {
            float z = z0 * 0.01f;
            float czt = c + z;
#pragma unroll 10
            for (int s = 0; s < 500; ++s) {
                float e = __builtin_amdgcn_exp2f(fmaf(v, L2E, K55));
                float w = fmaf(0.99f, v, czt);
                v = fmaf(0.01f, e, w);
                vmax = fmaxf(vmax, v);
                vmin = fminf(vmin, v);
                z *= 0.9875f;
                czt = c + z;
            }
        }
        // invalid speculation (clamp would have engaged / NaN) OR spike
        fb = (vmax >= 0.0f) || !(vmin >= -85.0f);
    }

    unsigned long long bal = __ballot(fb);
    if ((t & 63) == 0) m[t >> 6] = bal;
    __syncthreads();
    if (t == 0) sflags[blockIdx.x] = (m[0] | m[1] | m[2] | m[3]) ? 1 : 0;

    out[gid] = 0.0f;                             // overwritten by fallback if set
}

// ---------------- event-driven exact fallback (r3-proven), gated -----------

__global__ __launch_bounds__(1024) void persist_kernel(const float* __restrict__ W,
                                                       const float* __restrict__ x0,
                                                       const float* __restrict__ V0,
                                                       const int* __restrict__ sflags,
                                                       float* __restrict__ zrec,
                                                       float* __restrict__ out) {
    const int t = threadIdx.x;
    const int lane = t & 63;

    bool spk = false;
#pragma unroll
    for (int i = 0; i < 4; ++i) spk |= (sflags[lane + 64 * i] != 0);
    if (!__any(spk)) return;                     // uniform exit: before any barrier

    __shared__ unsigned long long masks[2][16];
    __shared__ int cnt;
    __shared__ int list[4096];

    const int b = blockIdx.x;
    const int wv = t >> 6;
    const int n0 = t * 4;
    const size_t base = (size_t)b * NN + n0;

    float4 zr = *(const float4*)(zrec + base);
    float4 v  = *(const float4*)(V0 + base);
    float4 xx = *(const float4*)(x0 + base);
    float4 r  = {0.0f, 0.0f, 0.0f, 0.0f};

#pragma unroll 1
    for (int step = 0; step < 500; ++step) {
        const int p = step & 1;

        float z0 = zr.x + xx.x, z1 = zr.y + xx.y, z2 = zr.z + xx.z, z3 = zr.w + xx.w;

        float e0 = expf(v.x + 55.0f), e1 = expf(v.y + 55.0f);
        float e2 = expf(v.z + 55.0f), e3 = expf(v.w + 55.0f);
        v.x = fmaxf(fmaf(0.01f, -(v.x + 72.0f) + e0 + z0, v.x), -85.0f);
        v.y = fmaxf(fmaf(0.01f, -(v.y + 72.0f) + e1 + z1, v.y), -85.0f);
        v.z = fmaxf(fmaf(0.01f, -(v.z + 72.0f) + e2 + z2, v.z), -85.0f);
        v.w = fmaxf(fmaf(0.01f, -(v.w + 72.0f) + e3 + z3, v.w), -85.0f);

        bool s0 = v.x >= 0.0f, s1 = v.y >= 0.0f, s2 = v.z >= 0.0f, s3 = v.w >= 0.0f;
        if (s0) { v.x = -72.0f; r.x += 10.0f; }
        if (s1) { v.y = -72.0f; r.y += 10.0f; }
        if (s2) { v.z = -72.0f; r.z += 10.0f; }
        if (s3) { v.w = -72.0f; r.w += 10.0f; }

        zr.x *= 0.9875f; zr.y *= 0.9875f; zr.z *= 0.9875f; zr.w *= 0.9875f;

        bool any = s0 | s1 | s2 | s3;
        unsigned long long bal = __ballot(any);
        if (lane == 0) masks[p][wv] = bal;
        __syncthreads();

        unsigned long long tot = 0;
#pragma unroll
        for (int i = 0; i < 16; ++i) tot |= masks[p][i];

        if (tot != 0) {
            if (t == 0) cnt = 0;
            __syncthreads();
            int k = (int)s0 + (int)s1 + (int)s2 + (int)s3;
            if (k) {
                int pos = atomicAdd(&cnt, k);
                if (s0) list[pos++] = n0 + 0;
                if (s1) list[pos++] = n0 + 1;
                if (s2) list[pos++] = n0 + 2;
                if (s3) list[pos++] = n0 + 3;
            }
            __syncthreads();
            int mcnt = cnt;
            for (int s = 0; s < mcnt; ++s) {
                int j = list[s];
                zr.x += 0.125f * W[(size_t)(n0 + 0) * NN + j];
                zr.y += 0.125f * W[(size_t)(n0 + 1) * NN + j];
                zr.z += 0.125f * W[(size_t)(n0 + 2) * NN + j];
                zr.w += 0.125f * W[(size_t)(n0 + 3) * NN + j];
            }
        }
    }

    float4 o = {r.x * 0.002f, r.y * 0.002f, r.z * 0.002f, r.w * 0.002f};
    *(float4*)(out + base) = o;
}

extern "C" void kernel_launch(void* const* d_in, const int* in_sizes, int n_in,
                              void* d_out, int out_size, void* d_ws, size_t ws_size,
                              hipStream_t stream) {
    const float* W  = (const float*)d_in[0];
    const float* x0 = (const float*)d_in[1];
    const float* V0 = (const float*)d_in[2];
    const float* Y0 = (const float*)d_in[3];
    float* out  = (float*)d_out;
    float* ws   = (float*)d_ws;

    float* zrec = ws;                            // 65536 floats
    int* sflags = (int*)(ws + 65536);            // 256 ints

    spec_kernel<<<256, 256, 0, stream>>>(W, x0, V0, Y0, zrec, sflags, out);
    persist_kernel<<<16, 1024, 0, stream>>>(W, x0, V0, sflags, zrec, out);
}

// Round 2
// 90.573 us; speedup vs baseline: 1.0900x; 1.0051x over previous
//
#include <hip/hip_runtime.h>
#include <math.h>

// SpikingModel: 500-step EIF recurrent net, B=16, N=4096, fp32.
// Round-9: SINGLE dispatch. Batch rows are independent (Y[b,:]@W^T only feeds
// row b), so the old spec->flags->persist split was over-conservative: each
// row-block can self-certify and, if needed, self-solve exactly.
//
//   fused_kernel (16 blocks x 1024 threads, 4 neurons/thread):
//     1. Load V0/x0/Y0 row slices (one float4/int4 per thread, coalesced).
//     2. Y0-row zero-scan via __syncthreads_or on raw bits (conservative,
//        NaN-safe: any nonzero bit pattern -> fallback).
//     3. Closed-form no-spike certificate, per neuron:
//          Y0row==0 (=> Z_t == x0, constant) && V0 <= -55 && x0 <= 8
//          =>  V' = 0.99V + 0.01(e^{V+55} + x0 - 72) <= -55.08  (margin 0.08
//          >> fp32 slop), and the -85 clamp maps into [-85,-55], so V <= -55
//          is invariant => zero spikes => out row == 0 exactly.
//        __syncthreads_and over the row: if all certified -> write 0, return.
//     4. Fallback (never taken on bench, exact): stage Y0 row in LDS, dense
//        z0 = Y0row @ W[n,:] per neuron, then the r3-proven event-driven
//        integration (spike list + column gather), write exact out row.
//
// NaN safety: NaN Y0 bits -> ynz -> fallback; NaN V0/x0 fail the <= compares
// -> fallback. Fallback is the exact reference recurrence.
//
// Workspace: unused.

#define NN 4096

__global__ __launch_bounds__(1024) void fused_kernel(const float* __restrict__ W,
                                                     const float* __restrict__ x0,
                                                     const float* __restrict__ V0,
                                                     const float* __restrict__ Y0,
                                                     float* __restrict__ out) {
    __shared__ float yrow[NN];                   // 16 KB (fallback dense dot)
    __shared__ unsigned long long masks[2][16];
    __shared__ int cnt;
    __shared__ int list[NN];                     // 16 KB spike list

    const int t = threadIdx.x;
    const int lane = t & 63;
    const int wv = t >> 6;
    const int b = blockIdx.x;
    const int n0 = t * 4;
    const size_t base = (size_t)b * NN + n0;

    // ---- coalesced row loads: 1 float4/int4 per thread ---------------------
    float4 v  = *(const float4*)(V0 + base);
    float4 xx = *(const float4*)(x0 + base);
    int4  yq  = *(const int4*)(Y0 + base);

    // ---- Y0 row zero-scan (bitwise OR, conservative) -----------------------
    const int ynz = __syncthreads_or(yq.x | yq.y | yq.z | yq.w);

    // ---- closed-form no-spike certificate ----------------------------------
    if (!ynz) {
        const bool ok = (v.x <= -55.0f) && (v.y <= -55.0f) &&
                        (v.z <= -55.0f) && (v.w <= -55.0f) &&
                        (xx.x <= 8.0f) && (xx.y <= 8.0f) &&
                        (xx.z <= 8.0f) && (xx.w <= 8.0f);
        if (__syncthreads_and((int)ok)) {        // whole row certified
            float4 zero = {0.0f, 0.0f, 0.0f, 0.0f};
            *(float4*)(out + base) = zero;
            return;
        }
    }

    // =========================== exact fallback =============================
    // z0 = Y0[b,:] @ W[n,:]  (recurrent input at step 0), per neuron.
    float4 zr = {0.0f, 0.0f, 0.0f, 0.0f};
    if (ynz) {
        ((float4*)yrow)[t] = *(const float4*)&yq;   // stage row in LDS
        __syncthreads();
        const float* W0 = W + (size_t)(n0 + 0) * NN;
        const float* W1 = W + (size_t)(n0 + 1) * NN;
        const float* W2 = W + (size_t)(n0 + 2) * NN;
        const float* W3 = W + (size_t)(n0 + 3) * NN;
        for (int j = 0; j < NN; j += 4) {
            float4 y  = ((const float4*)yrow)[j >> 2];
            float4 w0 = *(const float4*)(W0 + j);
            float4 w1 = *(const float4*)(W1 + j);
            float4 w2 = *(const float4*)(W2 + j);
            float4 w3 = *(const float4*)(W3 + j);
            zr.x = fmaf(y.x, w0.x, fmaf(y.y, w0.y, fmaf(y.z, w0.z, fmaf(y.w, w0.w, zr.x))));
            zr.y = fmaf(y.x, w1.x, fmaf(y.y, w1.y, fmaf(y.z, w1.z, fmaf(y.w, w1.w, zr.y))));
            zr.z = fmaf(y.x, w2.x, fmaf(y.y, w2.y, fmaf(y.z, w2.z, fmaf(y.w, w2.w, zr.z))));
            zr.w = fmaf(y.x, w3.x, fmaf(y.y, w3.y, fmaf(y.z, w3.z, fmaf(y.w, w3.w, zr.w))));
        }
        __syncthreads();
    }

    float4 r = {0.0f, 0.0f, 0.0f, 0.0f};

#pragma unroll 1
    for (int step = 0; step < 500; ++step) {
        const int p = step & 1;

        float z0 = zr.x + xx.x, z1 = zr.y + xx.y, z2 = zr.z + xx.z, z3 = zr.w + xx.w;

        float e0 = expf(v.x + 55.0f), e1 = expf(v.y + 55.0f);
        float e2 = expf(v.z + 55.0f), e3 = expf(v.w + 55.0f);
        v.x = fmaxf(fmaf(0.01f, -(v.x + 72.0f) + e0 + z0, v.x), -85.0f);
        v.y = fmaxf(fmaf(0.01f, -(v.y + 72.0f) + e1 + z1, v.y), -85.0f);
        v.z = fmaxf(fmaf(0.01f, -(v.z + 72.0f) + e2 + z2, v.z), -85.0f);
        v.w = fmaxf(fmaf(0.01f, -(v.w + 72.0f) + e3 + z3, v.w), -85.0f);

        bool s0 = v.x >= 0.0f, s1 = v.y >= 0.0f, s2 = v.z >= 0.0f, s3 = v.w >= 0.0f;
        if (s0) { v.x = -72.0f; r.x += 10.0f; }
        if (s1) { v.y = -72.0f; r.y += 10.0f; }
        if (s2) { v.z = -72.0f; r.z += 10.0f; }
        if (s3) { v.w = -72.0f; r.w += 10.0f; }

        zr.x *= 0.9875f; zr.y *= 0.9875f; zr.z *= 0.9875f; zr.w *= 0.9875f;

        bool any = s0 | s1 | s2 | s3;
        unsigned long long bal = __ballot(any);
        if (lane == 0) masks[p][wv] = bal;
        __syncthreads();

        unsigned long long tot = 0;
#pragma unroll
        for (int i = 0; i < 16; ++i) tot |= masks[p][i];

        if (tot != 0) {
            if (t == 0) cnt = 0;
            __syncthreads();
            int k = (int)s0 + (int)s1 + (int)s2 + (int)s3;
            if (k) {
                int pos = atomicAdd(&cnt, k);
                if (s0) list[pos++] = n0 + 0;
                if (s1) list[pos++] = n0 + 1;
                if (s2) list[pos++] = n0 + 2;
                if (s3) list[pos++] = n0 + 3;
            }
            __syncthreads();
            int mcnt = cnt;
            for (int s = 0; s < mcnt; ++s) {
                int j = list[s];
                zr.x += 0.125f * W[(size_t)(n0 + 0) * NN + j];
                zr.y += 0.125f * W[(size_t)(n0 + 1) * NN + j];
                zr.z += 0.125f * W[(size_t)(n0 + 2) * NN + j];
                zr.w += 0.125f * W[(size_t)(n0 + 3) * NN + j];
            }
        }
    }

    float4 o = {r.x * 0.002f, r.y * 0.002f, r.z * 0.002f, r.w * 0.002f};
    *(float4*)(out + base) = o;
}

extern "C" void kernel_launch(void* const* d_in, const int* in_sizes, int n_in,
                              void* d_out, int out_size, void* d_ws, size_t ws_size,
                              hipStream_t stream) {
    const float* W  = (const float*)d_in[0];
    const float* x0 = (const float*)d_in[1];
    const float* V0 = (const float*)d_in[2];
    const float* Y0 = (const float*)d_in[3];
    float* out = (float*)d_out;
    (void)d_ws; (void)ws_size;

    fused_kernel<<<16, 1024, 0, stream>>>(W, x0, V0, Y0, out);
}

// Round 3
// 89.875 us; speedup vs baseline: 1.0984x; 1.0078x over previous
//
#include <hip/hip_runtime.h>
#include <math.h>

// SpikingModel: 500-step EIF recurrent net, B=16, N=4096, fp32.
// Round-10: critical-chain trim of the certificate hot path.
//   - out=0 store hoisted BEFORE the loads (no dependency -> retires under
//     load latency + barrier; fallback path overwrites in program order).
//   - Y0 zero-scan and certificate merged into ONE __syncthreads_and
//     (was: __syncthreads_or + __syncthreads_and = two 16-wave reductions).
//     Fallback recomputes ynz with its own __syncthreads_or (cold path only).
//
//   fused_kernel (16 blocks x 1024 threads, 4 neurons/thread):
//     Certificate, per neuron:  Y0row==0 (=> Z_t == x0 constant) &&
//     V0 <= -55 && x0 <= 8  =>  V' = 0.99V + 0.01(e^{V+55} + x0 - 72)
//     <= -55.08 (margin 0.08 >> fp32 slop), -85 clamp maps into [-85,-55],
//     so V <= -55 is invariant => zero spikes => out row == 0 exactly.
//     One __syncthreads_and over the row: all certified -> return (zeros
//     already written). Else: exact r3-proven event-driven fallback.
//
// NaN safety: NaN Y0 bits -> nonzero -> not certified; NaN V0/x0 fail the
// <= compares -> not certified. Fallback is the exact reference recurrence.
//
// Workspace: unused.

#define NN 4096

__global__ __launch_bounds__(1024) void fused_kernel(const float* __restrict__ W,
                                                     const float* __restrict__ x0,
                                                     const float* __restrict__ V0,
                                                     const float* __restrict__ Y0,
                                                     float* __restrict__ out) {
    __shared__ float yrow[NN];                   // 16 KB (fallback dense dot)
    __shared__ unsigned long long masks[2][16];
    __shared__ int cnt;
    __shared__ int list[NN];                     // 16 KB spike list

    const int t = threadIdx.x;
    const int lane = t & 63;
    const int wv = t >> 6;
    const int b = blockIdx.x;
    const int n0 = t * 4;
    const size_t base = (size_t)b * NN + n0;

    // ---- early zero-store: no deps, hides under loads + barrier ------------
    {
        float4 zero = {0.0f, 0.0f, 0.0f, 0.0f};
        *(float4*)(out + base) = zero;
    }

    // ---- coalesced row loads: 1 float4/int4 per thread (independent) -------
    float4 v  = *(const float4*)(V0 + base);
    float4 xx = *(const float4*)(x0 + base);
    int4  yq  = *(const int4*)(Y0 + base);

    // ---- single fused reduction: Y0==0 && per-neuron certificate -----------
    const bool ok = ((yq.x | yq.y | yq.z | yq.w) == 0) &&
                    (v.x <= -55.0f) && (v.y <= -55.0f) &&
                    (v.z <= -55.0f) && (v.w <= -55.0f) &&
                    (xx.x <= 8.0f) && (xx.y <= 8.0f) &&
                    (xx.z <= 8.0f) && (xx.w <= 8.0f);
    if (__syncthreads_and((int)ok)) return;      // row certified: out already 0

    // =========================== exact fallback =============================
    // Need ynz (whole-row Y0 nonzero?) separately here: cold path only.
    const int ynz = __syncthreads_or(yq.x | yq.y | yq.z | yq.w);

    // z0 = Y0[b,:] @ W[n,:]  (recurrent input at step 0), per neuron.
    float4 zr = {0.0f, 0.0f, 0.0f, 0.0f};
    if (ynz) {
        ((float4*)yrow)[t] = *(const float4*)&yq;   // stage row in LDS
        __syncthreads();
        const float* W0 = W + (size_t)(n0 + 0) * NN;
        const float* W1 = W + (size_t)(n0 + 1) * NN;
        const float* W2 = W + (size_t)(n0 + 2) * NN;
        const float* W3 = W + (size_t)(n0 + 3) * NN;
        for (int j = 0; j < NN; j += 4) {
            float4 y  = ((const float4*)yrow)[j >> 2];
            float4 w0 = *(const float4*)(W0 + j);
            float4 w1 = *(const float4*)(W1 + j);
            float4 w2 = *(const float4*)(W2 + j);
            float4 w3 = *(const float4*)(W3 + j);
            zr.x = fmaf(y.x, w0.x, fmaf(y.y, w0.y, fmaf(y.z, w0.z, fmaf(y.w, w0.w, zr.x))));
            zr.y = fmaf(y.x, w1.x, fmaf(y.y, w1.y, fmaf(y.z, w1.z, fmaf(y.w, w1.w, zr.y))));
            zr.z = fmaf(y.x, w2.x, fmaf(y.y, w2.y, fmaf(y.z, w2.z, fmaf(y.w, w2.w, zr.z))));
            zr.w = fmaf(y.x, w3.x, fmaf(y.y, w3.y, fmaf(y.z, w3.z, fmaf(y.w, w3.w, zr.w))));
        }
        __syncthreads();
    }

    float4 r = {0.0f, 0.0f, 0.0f, 0.0f};

#pragma unroll 1
    for (int step = 0; step < 500; ++step) {
        const int p = step & 1;

        float z0 = zr.x + xx.x, z1 = zr.y + xx.y, z2 = zr.z + xx.z, z3 = zr.w + xx.w;

        float e0 = expf(v.x + 55.0f), e1 = expf(v.y + 55.0f);
        float e2 = expf(v.z + 55.0f), e3 = expf(v.w + 55.0f);
        v.x = fmaxf(fmaf(0.01f, -(v.x + 72.0f) + e0 + z0, v.x), -85.0f);
        v.y = fmaxf(fmaf(0.01f, -(v.y + 72.0f) + e1 + z1, v.y), -85.0f);
        v.z = fmaxf(fmaf(0.01f, -(v.z + 72.0f) + e2 + z2, v.z), -85.0f);
        v.w = fmaxf(fmaf(0.01f, -(v.w + 72.0f) + e3 + z3, v.w), -85.0f);

        bool s0 = v.x >= 0.0f, s1 = v.y >= 0.0f, s2 = v.z >= 0.0f, s3 = v.w >= 0.0f;
        if (s0) { v.x = -72.0f; r.x += 10.0f; }
        if (s1) { v.y = -72.0f; r.y += 10.0f; }
        if (s2) { v.z = -72.0f; r.z += 10.0f; }
        if (s3) { v.w = -72.0f; r.w += 10.0f; }

        zr.x *= 0.9875f; zr.y *= 0.9875f; zr.z *= 0.9875f; zr.w *= 0.9875f;

        bool any = s0 | s1 | s2 | s3;
        unsigned long long bal = __ballot(any);
        if (lane == 0) masks[p][wv] = bal;
        __syncthreads();

        unsigned long long tot = 0;
#pragma unroll
        for (int i = 0; i < 16; ++i) tot |= masks[p][i];

        if (tot != 0) {
            if (t == 0) cnt = 0;
            __syncthreads();
            int k = (int)s0 + (int)s1 + (int)s2 + (int)s3;
            if (k) {
                int pos = atomicAdd(&cnt, k);
                if (s0) list[pos++] = n0 + 0;
                if (s1) list[pos++] = n0 + 1;
                if (s2) list[pos++] = n0 + 2;
                if (s3) list[pos++] = n0 + 3;
            }
            __syncthreads();
            int mcnt = cnt;
            for (int s = 0; s < mcnt; ++s) {
                int j = list[s];
                zr.x += 0.125f * W[(size_t)(n0 + 0) * NN + j];
                zr.y += 0.125f * W[(size_t)(n0 + 1) * NN + j];
                zr.z += 0.125f * W[(size_t)(n0 + 2) * NN + j];
                zr.w += 0.125f * W[(size_t)(n0 + 3) * NN + j];
            }
        }
    }

    float4 o = {r.x * 0.002f, r.y * 0.002f, r.z * 0.002f, r.w * 0.002f};
    *(float4*)(out + base) = o;
}

extern "C" void kernel_launch(void* const* d_in, const int* in_sizes, int n_in,
                              void* d_out, int out_size, void* d_ws, size_t ws_size,
                              hipStream_t stream) {
    const float* W  = (const float*)d_in[0];
    const float* x0 = (const float*)d_in[1];
    const float* V0 = (const float*)d_in[2];
    const float* Y0 = (const float*)d_in[3];
    float* out = (float*)d_out;
    (void)d_ws; (void)ws_size;

    fused_kernel<<<16, 1024, 0, stream>>>(W, x0, V0, Y0, out);
}